// Round 1
// baseline (155.907 us; speedup 1.0000x reference)
//
#include <hip/hip_runtime.h>
#include <math.h>

// CellList dense masked-distance map, N=6144, no PBC.
// out[i*N+j] = |r_i - r_j| if (i>j && species_i!=-1 && species_j!=-1 &&
//                              dist<=cutoff && sq>0) else 0.
//
// R6 = R5 structure, but LANE-CONTIGUOUS stores. R5 had each thread own 8
// consecutive columns (lane stride 32 B), so every wave store_dwordx4 wrote
// 1 KB scattered over a 2 KB span (50% fill; every 64 B line touched by two
// instructions). Now each thread owns cols [base+tid*4) and [base+1024+tid*4):
// each wave store instruction is a fully-dense contiguous 1 KB segment.
//  - 3072 blocks (12/CU); each block = one 2048-col strip x 6 consecutive
//    rows. j-side coords/species loaded ONCE per thread, reused across the
//    6 rows.
//  - upper-triangle / dummy rows: pure zero stores, no loads/math.
//  - mask via sq <= T (T = largest f32 with sqrt_rn(T) <= cutoff) -- bit-
//    exact vs reference (absmax 0.0 in prior rounds), no per-element IEEE
//    sqrt.
//  - dist via raw v_sqrt_f32 (1 ulp; threshold 0.1).
//  - sq in numpy's ((x*x + y*y) + z*z) order, no FMA contraction.

constexpr int N      = 6144;
constexpr int BLOCK  = 256;
constexpr int CPB    = 2048;         // columns per block
constexpr int HALF   = CPB / 2;      // 1024: two contiguous 4-col chunks/thread
constexpr int NSTRIP = N / CPB;      // 3 column strips
constexpr int RPB    = 6;            // rows per block
constexpr int NROWG  = N / RPB;      // 1024 row groups

__global__ __launch_bounds__(BLOCK) void cell_list_kernel(
    const float* __restrict__ coords,   // [N][3] f32
    const int*   __restrict__ species,  // [N] i32
    const int*   __restrict__ cutoff_p, // [1] i32
    float*       __restrict__ out)      // [N][N] f32
{
    const int bx    = blockIdx.x;
    const int strip = bx % NSTRIP;
    const int i0    = (bx / NSTRIP) * RPB;
    const int base  = strip * CPB;
    const int jA    = base + (int)threadIdx.x * 4;  // chunk A: contiguous across wave
    const int jB    = jA + HALF;                    // chunk B: contiguous across wave

    // T = largest f32 x with sqrt_rn(x) <= c: sqrt_rn(x) <= c iff
    // sqrt_exact(x) < c + 0.5*ulp(c) (tie impossible: midpoint^2 not f32-
    // representable). Exact in double, rounded down. Scalar, once.
    const float  c  = (float)cutoff_p[0];
    const float  cn = __int_as_float(__float_as_int(c) + 1);
    const double md = (double)c + 0.5 * ((double)cn - (double)c);
    const double Td = md * md;
    float T = (float)Td;
    if ((double)T > Td) T = __int_as_float(__float_as_int(T) - 1);

    // Load j-side data once per thread iff any row in this block computes.
    float fA[12], fB[12];
    int   sA[4],  sB[4];
    if (i0 + RPB - 1 > base) {
        const float4* ca = reinterpret_cast<const float4*>(coords + 3 * (size_t)jA);
        const float4* cb = reinterpret_cast<const float4*>(coords + 3 * (size_t)jB);
#pragma unroll
        for (int q = 0; q < 3; ++q) {
            const float4 va = ca[q];
            fA[4 * q + 0] = va.x; fA[4 * q + 1] = va.y;
            fA[4 * q + 2] = va.z; fA[4 * q + 3] = va.w;
            const float4 vb = cb[q];
            fB[4 * q + 0] = vb.x; fB[4 * q + 1] = vb.y;
            fB[4 * q + 2] = vb.z; fB[4 * q + 3] = vb.w;
        }
        const int4 sa = *reinterpret_cast<const int4*>(species + jA);
        const int4 sb = *reinterpret_cast<const int4*>(species + jB);
        sA[0] = sa.x; sA[1] = sa.y; sA[2] = sa.z; sA[3] = sa.w;
        sB[0] = sb.x; sB[1] = sb.y; sB[2] = sb.z; sB[3] = sb.w;
    }

    const float4 zero4 = make_float4(0.f, 0.f, 0.f, 0.f);

    for (int rr = 0; rr < RPB; ++rr) {
        const int i = i0 + rr;
        float4* ovA = reinterpret_cast<float4*>(out + (size_t)i * N + jA);
        float4* ovB = reinterpret_cast<float4*>(out + (size_t)i * N + jB);
        const int si = species[i];  // block-uniform -> scalar load

        if (i <= base || si == -1) {  // whole strip j >= i, or dummy row
            *ovA = zero4;
            *ovB = zero4;
            continue;
        }

        const float xi = coords[3 * i + 0];
        const float yi = coords[3 * i + 1];
        const float zi = coords[3 * i + 2];

        float rA[4], rB[4];
#pragma unroll
        for (int k = 0; k < 4; ++k) {
            // Exact numpy order: (dx*dx + dy*dy) + dz*dz, no FMA.
            {
                const float dx = __fsub_rn(xi, fA[3 * k + 0]);
                const float dy = __fsub_rn(yi, fA[3 * k + 1]);
                const float dz = __fsub_rn(zi, fA[3 * k + 2]);
                const float sq = __fadd_rn(
                    __fadd_rn(__fmul_rn(dx, dx), __fmul_rn(dy, dy)),
                    __fmul_rn(dz, dz));
                const bool m = (sq <= T) && (sA[k] != -1) && (jA + k < i);
                rA[k] = m ? __builtin_amdgcn_sqrtf(sq) : 0.0f;
            }
            {
                const float dx = __fsub_rn(xi, fB[3 * k + 0]);
                const float dy = __fsub_rn(yi, fB[3 * k + 1]);
                const float dz = __fsub_rn(zi, fB[3 * k + 2]);
                const float sq = __fadd_rn(
                    __fadd_rn(__fmul_rn(dx, dx), __fmul_rn(dy, dy)),
                    __fmul_rn(dz, dz));
                const bool m = (sq <= T) && (sB[k] != -1) && (jB + k < i);
                rB[k] = m ? __builtin_amdgcn_sqrtf(sq) : 0.0f;
            }
        }
        *ovA = make_float4(rA[0], rA[1], rA[2], rA[3]);
        *ovB = make_float4(rB[0], rB[1], rB[2], rB[3]);
    }
}

extern "C" void kernel_launch(void* const* d_in, const int* in_sizes, int n_in,
                              void* d_out, int out_size, void* d_ws, size_t ws_size,
                              hipStream_t stream) {
    // setup_inputs() order: species (i32 [1,N]), coordinates (f32 [1,N,3]),
    // cutoff (python int -> i32 [1]).
    const int*   species = (const int*)d_in[0];
    const float* coords  = (const float*)d_in[1];
    const int*   cutoff  = (const int*)d_in[2];
    float*       out     = (float*)d_out;

    dim3 block(BLOCK);
    dim3 grid(NSTRIP * NROWG);  // 3072 blocks = 12/CU
    hipLaunchKernelGGL(cell_list_kernel, grid, block, 0, stream,
                       coords, species, cutoff, out);
}